// Round 3
// baseline (71.067 us; speedup 1.0000x reference)
//
#include <hip/hip_runtime.h>
#include <math.h>

#define BB 8
#define CC 512
#define HWSZ 6400
#define NN 100
#define HR 40
#define WR 40
#define VV 20        // N_CLASSES_FG
#define VO 21        // BG + FG
#define TPX 128      // pixels per tile in K2/K4
#define NTILE (HWSZ / TPX)   // 50

typedef unsigned long long u64;

// order-preserving float -> uint32 map (min float == min uint)
__device__ __forceinline__ unsigned mapf(float f) {
    unsigned b = __float_as_uint(f);
    return (b & 0x80000000u) ? ~b : (b | 0x80000000u);
}

// ---------------- K1: normalized prototypes, transposed [c][v]; init batchMin
__global__ __launch_bounds__(512) void k_protos(const float* __restrict__ refc,
                                                const int* __restrict__ coord,
                                                const int* __restrict__ cls,
                                                float* __restrict__ protosT,
                                                u64* __restrict__ batchMin) {
    const int v = blockIdx.x;        // class
    const int c = threadIdx.x;       // channel
    if (v == 0 && c < BB) batchMin[c] = ~0ull;

    float acc = 0.f;
    int cnt = 0;
    for (int n = 0; n < NN; ++n) {
        if (cls[n] == v) {           // uniform across block
            int y = coord[2 * n + 1];
            int x = coord[2 * n + 0];
            acc += refc[((size_t)(n * CC + c) * HR + y) * WR + x];
            ++cnt;
        }
    }
    acc /= fmaxf((float)cnt, 1.0f);

    float ss = acc * acc;
    #pragma unroll
    for (int off = 32; off; off >>= 1) ss += __shfl_xor(ss, off);
    __shared__ float sW[8];
    const int wave = c >> 6, lane = c & 63;
    if (lane == 0) sW[wave] = ss;
    __syncthreads();
    float tot = 0.f;
    #pragma unroll
    for (int w = 0; w < 8; ++w) tot += sW[w];
    float scale = 1.0f / fmaxf(sqrtf(tot), 1e-10f);

    protosT[c * VV + v] = acc * scale;
}

// ---------------- K2: prob_C + per-pixel sum + fused block argmin -----------
// grid = 8 b x 50 tiles(128px); block = 256 = 4 waves; wave w -> channels
// [w*128, w*128+128); lane -> pixel pair (2*lane, 2*lane+1). float2 loads,
// protos via SGPR s_load (channel is wave-uniform).
__global__ __launch_bounds__(256, 2) void k_probC(const float* __restrict__ codeC,
                                                  const float* __restrict__ protosT,
                                                  float* __restrict__ probC,
                                                  u64* __restrict__ batchMin) {
    __shared__ float red[4 * VO * TPX];   // 43 KB
    __shared__ float sScale[TPX];
    __shared__ float sPart[2 * TPX];
    __shared__ u64 sKey[2];

    const int tid  = threadIdx.x;
    const int wave = tid >> 6, lane = tid & 63;
    const int b    = blockIdx.x / NTILE;
    const int tile = blockIdx.x % NTILE;
    const int c0   = __builtin_amdgcn_readfirstlane(wave * 128);

    const float* src = codeC + ((size_t)(b * CC + c0)) * HWSZ + tile * TPX + 2 * lane;
    const float* pt  = protosT + (size_t)c0 * VV;   // uniform -> s_load

    float2 d[VV];
    #pragma unroll
    for (int v = 0; v < VV; ++v) d[v] = make_float2(0.f, 0.f);
    float2 ss = make_float2(0.f, 0.f);

    #pragma unroll 8
    for (int c = 0; c < 128; ++c) {
        float2 x = *(const float2*)(src + (size_t)c * HWSZ);
        ss.x = fmaf(x.x, x.x, ss.x);
        ss.y = fmaf(x.y, x.y, ss.y);
        const float* pr = pt + c * VV;
        #pragma unroll
        for (int v = 0; v < VV; ++v) {
            float p = pr[v];
            d[v].x = fmaf(x.x, p, d[v].x);
            d[v].y = fmaf(x.y, p, d[v].y);
        }
    }

    // cross-wave reduction: red[w][v][px]
    #pragma unroll
    for (int v = 0; v < VV; ++v) {
        red[wave * (VO * TPX) + v * TPX + 2 * lane    ] = d[v].x;
        red[wave * (VO * TPX) + v * TPX + 2 * lane + 1] = d[v].y;
    }
    red[wave * (VO * TPX) + VV * TPX + 2 * lane    ] = ss.x;
    red[wave * (VO * TPX) + VV * TPX + 2 * lane + 1] = ss.y;
    __syncthreads();

    float psum = 0.f;
    for (int q = tid; q < VO * TPX; q += 256) {
        float t = red[q] + red[VO * TPX + q] + red[2 * VO * TPX + q] + red[3 * VO * TPX + q];
        red[q] = t;                      // each q owned by exactly one thread
        if (q < VV * TPX) psum += t;     // thread's px = tid & 127 is fixed
    }
    __syncthreads();
    if (tid < TPX) sScale[tid] = 1.0f / fmaxf(sqrtf(red[VV * TPX + tid]), 1e-10f);
    sPart[(tid >> 7) * TPX + (tid & 127)] = psum;
    __syncthreads();

    // store probC (scaled)
    float* dst = probC + (size_t)b * VV * HWSZ + tile * TPX;
    for (int q = tid; q < VV * TPX; q += 256) {
        int v = q >> 7, px = q & 127;
        dst[(size_t)v * HWSZ + px] = red[q] * sScale[px];
    }

    // block-local argmin of per-pixel sums -> device atomicMin
    if (tid < TPX) {
        float total = (sPart[tid] + sPart[TPX + tid]) * sScale[tid];
        u64 key = ((u64)mapf(total) << 32) | (unsigned)(tile * TPX + tid);
        #pragma unroll
        for (int off = 32; off; off >>= 1) {
            u64 o = __shfl_xor(key, off);
            if (o < key) key = o;
        }
        if ((tid & 63) == 0) sKey[tid >> 6] = key;
    }
    __syncthreads();
    if (tid == 0) {
        u64 k = sKey[0] < sKey[1] ? sKey[0] : sKey[1];
        atomicMin(&batchMin[b], k);
    }
}

// ---------------- K3n: normalize code_BG at the argmin pixel ----------------
__global__ __launch_bounds__(512) void k_minvec(const u64* __restrict__ batchMin,
                                                const float* __restrict__ codeBG,
                                                float* __restrict__ minvecN) {
    const int b = blockIdx.x, c = threadIdx.x;
    const int pix = (int)(unsigned)(batchMin[b] & 0xFFFFFFFFull);
    float x = codeBG[(size_t)(b * CC + c) * HWSZ + pix];
    float ss = x * x;
    #pragma unroll
    for (int off = 32; off; off >>= 1) ss += __shfl_xor(ss, off);
    __shared__ float sW[8];
    if ((c & 63) == 0) sW[c >> 6] = ss;
    __syncthreads();
    float tot = 0.f;
    #pragma unroll
    for (int w = 0; w < 8; ++w) tot += sW[w];
    minvecN[b * CC + c] = x * (1.0f / fmaxf(sqrtf(tot), 1e-10f));
}

// ---------------- K4: prob_BG + fused softmax + output ----------------------
// Same 4-wave x 128-channel, float2-pixel-pair structure as K2.
__global__ __launch_bounds__(256, 2) void k_bg_softmax(const float* __restrict__ codeBG,
                                                       const float* __restrict__ minvecN,
                                                       const float* __restrict__ probC,
                                                       float* __restrict__ out) {
    __shared__ float red2[4 * 2 * TPX];   // 4 KB
    __shared__ float sExp[VO * TPX];      // 10.75 KB
    __shared__ float sInv[TPX];

    const int tid  = threadIdx.x;
    const int wave = tid >> 6, lane = tid & 63;
    const int b    = blockIdx.x / NTILE;
    const int tile = blockIdx.x % NTILE;
    const int c0   = __builtin_amdgcn_readfirstlane(wave * 128);

    const float* src = codeBG + ((size_t)(b * CC + c0)) * HWSZ + tile * TPX + 2 * lane;
    const float* mv  = minvecN + b * CC + c0;   // uniform -> s_load

    float2 ss = make_float2(0.f, 0.f), dg = make_float2(0.f, 0.f);
    #pragma unroll 8
    for (int c = 0; c < 128; ++c) {
        float2 x = *(const float2*)(src + (size_t)c * HWSZ);
        float m = mv[c];
        ss.x = fmaf(x.x, x.x, ss.x);
        ss.y = fmaf(x.y, x.y, ss.y);
        dg.x = fmaf(x.x, m, dg.x);
        dg.y = fmaf(x.y, m, dg.y);
    }
    red2[wave * (2 * TPX) + 2 * lane    ] = ss.x;
    red2[wave * (2 * TPX) + 2 * lane + 1] = ss.y;
    red2[wave * (2 * TPX) + TPX + 2 * lane    ] = dg.x;
    red2[wave * (2 * TPX) + TPX + 2 * lane + 1] = dg.y;
    __syncthreads();
    {
        int q = tid;   // 256 threads cover 2*TPX exactly
        float t = red2[q] + red2[2 * TPX + q] + red2[4 * TPX + q] + red2[6 * TPX + q];
        red2[q] = t;
    }
    __syncthreads();

    if (tid < TPX) {
        const int px = tid;
        float pbg = red2[TPX + px] * (1.0f / fmaxf(sqrtf(red2[px]), 1e-10f));
        const float* pc = probC + (size_t)b * VV * HWSZ + tile * TPX + px;
        float pv[VO];
        pv[0] = pbg;
        #pragma unroll
        for (int v = 0; v < VV; ++v) pv[v + 1] = pc[(size_t)v * HWSZ];
        float m = pv[0];
        #pragma unroll
        for (int i = 1; i < VO; ++i) m = fmaxf(m, pv[i]);
        float se = 0.f;
        #pragma unroll
        for (int i = 0; i < VO; ++i) {
            float e = __expf(pv[i] - m);
            sExp[i * TPX + px] = e;
            se += e;
        }
        sInv[px] = 1.0f / se;
    }
    __syncthreads();

    float* dst = out + (size_t)b * VO * HWSZ + tile * TPX;
    for (int q = tid; q < VO * TPX; q += 256) {
        int v = q >> 7, px = q & 127;
        dst[(size_t)v * HWSZ + px] = sExp[q] * sInv[px];
    }
}

extern "C" void kernel_launch(void* const* d_in, const int* in_sizes, int n_in,
                              void* d_out, int out_size, void* d_ws, size_t ws_size,
                              hipStream_t stream) {
    const float* codeC  = (const float*)d_in[0];
    const float* codeBG = (const float*)d_in[1];
    const float* refc   = (const float*)d_in[2];
    // d_in[3] (ref_code_bg) unused by the reference
    const int* coord = (const int*)d_in[4];
    const int* cls   = (const int*)d_in[5];
    float* out = (float*)d_out;

    char* ws = (char*)d_ws;
    float* protosT  = (float*)(ws);                    // 40,960 B  [c][v]
    float* probC    = (float*)(ws + 40960);            // 4,096,000 B
    float* minvecN  = (float*)(ws + 4136960);          // 16,384 B
    u64*   batchMin = (u64*)  (ws + 4153344);          // 64 B

    k_protos    <<<dim3(VV),        dim3(512), 0, stream>>>(refc, coord, cls, protosT, batchMin);
    k_probC     <<<dim3(BB * NTILE), dim3(256), 0, stream>>>(codeC, protosT, probC, batchMin);
    k_minvec    <<<dim3(BB),        dim3(512), 0, stream>>>(batchMin, codeBG, minvecN);
    k_bg_softmax<<<dim3(BB * NTILE), dim3(256), 0, stream>>>(codeBG, minvecN, probC, out);
}